// Round 1
// baseline (184.789 us; speedup 1.0000x reference)
//
#include <hip/hip_runtime.h>

#define NIN  128
#define NOUT 128
#define NN   256   // N
#define BB   4     // batch

// One block per (b, o): 512 blocks, 256 threads.
// Phase 1: u{i,j}[b,o,t] = sum_c W{i,j}[o,c] * node[b,c,t]   -> LDS
// Phase 2: out[b,o,i,j] = adj[b,i,j] * (i==j ? ui[j] : uj[j]) -> float4 stores
__global__ __launch_bounds__(256) void nodeconv_kernel(
    const float* __restrict__ adj,   // [B,1,N,N]
    const float* __restrict__ node,  // [B,NIN,N]
    const float* __restrict__ Wi,    // [NOUT,NIN]
    const float* __restrict__ Wj,    // [NOUT,NIN]
    float* __restrict__ out)         // [B,NOUT,N,N]
{
    __shared__ float si[NN];
    __shared__ float sj[NN];

    const int bo = blockIdx.x;        // b*NOUT + o
    const int b  = bo >> 7;           // / NOUT
    const int o  = bo & (NOUT - 1);
    const int t  = threadIdx.x;       // 0..255 == column j for phase 1

    // ---- Phase 1: tiny per-(b,o) channel contraction ----
    {
        const float* np_ = node + (size_t)(b * NIN) * NN + t;  // stride NN over c
        const float* wi  = Wi + o * NIN;                       // block-uniform -> sgpr loads
        const float* wj  = Wj + o * NIN;
        float ai = 0.f, aj = 0.f;
        #pragma unroll 8
        for (int c = 0; c < NIN; ++c) {
            const float n = np_[(size_t)c * NN];
            ai += wi[c] * n;
            aj += wj[c] * n;
        }
        si[t] = ai;
        sj[t] = aj;
    }
    __syncthreads();

    // ---- Phase 2: stream the 256x256 tile ----
    const int j4   = t & 63;          // float4 column index (fixed per thread)
    const int jb   = j4 << 2;         // base column
    const int rrow = t >> 6;          // 0..3: row within each group of 4

    // j never changes for this thread: hoist the off-diagonal values.
    const float4 vj = *(const float4*)&sj[jb];

    const float* adjb = adj + (size_t)b * (NN * NN);
    float*       outp = out + (size_t)bo * (NN * NN);

    #pragma unroll 4
    for (int r = 0; r < 64; ++r) {
        const int i = (r << 2) + rrow;
        const float s_ii = si[i];                       // wave-uniform LDS broadcast
        const float4 a = *(const float4*)&adjb[i * NN + jb];
        float4 v;
        v.x = (i == jb + 0) ? s_ii : vj.x;
        v.y = (i == jb + 1) ? s_ii : vj.y;
        v.z = (i == jb + 2) ? s_ii : vj.z;
        v.w = (i == jb + 3) ? s_ii : vj.w;
        float4 rs;
        rs.x = a.x * v.x;
        rs.y = a.y * v.y;
        rs.z = a.z * v.z;
        rs.w = a.w * v.w;
        *(float4*)&outp[i * NN + jb] = rs;
    }
}

extern "C" void kernel_launch(void* const* d_in, const int* in_sizes, int n_in,
                              void* d_out, int out_size, void* d_ws, size_t ws_size,
                              hipStream_t stream) {
    const float* adj  = (const float*)d_in[0];  // [4,1,256,256]
    const float* node = (const float*)d_in[1];  // [4,128,256]
    const float* Wi   = (const float*)d_in[2];  // [128,128]
    const float* Wj   = (const float*)d_in[3];  // [128,128]
    float* out = (float*)d_out;                 // [4,128,256,256]

    dim3 grid(BB * NOUT);   // 512 blocks
    dim3 block(256);
    nodeconv_kernel<<<grid, block, 0, stream>>>(adj, node, Wi, Wj, out);
}

// Round 2
// 148.435 us; speedup vs baseline: 1.2449x; 1.2449x over previous
//
#include <hip/hip_runtime.h>

#define NIN  128
#define NOUT 128
#define NN   256   // N
#define BB   4     // batch

// ---------------- Kernel A: u{i,j}[b,o,j] = sum_c W{i,j}[o,c] * node[b,c,j] ----------------
// 512 blocks (one per b,o), 256 threads (one per j). Writes 2 x 512 KB to ws.
__global__ __launch_bounds__(256) void precompute_u(
    const float* __restrict__ node,  // [B,NIN,N]
    const float* __restrict__ Wi,    // [NOUT,NIN]
    const float* __restrict__ Wj,    // [NOUT,NIN]
    float* __restrict__ ui,          // [B*NOUT, N]
    float* __restrict__ uj)          // [B*NOUT, N]
{
    const int bo = blockIdx.x;
    const int b  = bo >> 7;
    const int o  = bo & (NOUT - 1);
    const int t  = threadIdx.x;

    const float* np_ = node + (size_t)b * NIN * NN + t;  // coalesced across lanes
    const float* wi  = Wi + o * NIN;                     // block-uniform -> scalar loads
    const float* wj  = Wj + o * NIN;

    float ai = 0.f, aj = 0.f;
    #pragma unroll 16
    for (int c = 0; c < NIN; ++c) {
        const float n = np_[c * NN];
        ai = fmaf(wi[c], n, ai);
        aj = fmaf(wj[c], n, aj);
    }
    ui[bo * NN + t] = ai;
    uj[bo * NN + t] = aj;
}

// ---------------- Kernel B: out[b,o,i,j] = adj[b,i,j] * (i==j ? ui[j] : uj[j]) -------------
// 4096 blocks: (b,o) x 8 row-chunks of 32 rows. 256 threads: 64 float4 cols x 4 rows.
__global__ __launch_bounds__(256) void stream_out(
    const float* __restrict__ adj,   // [B,1,N,N]
    const float* __restrict__ ui,    // [B*NOUT, N]
    const float* __restrict__ uj,    // [B*NOUT, N]
    float* __restrict__ out)         // [B,NOUT,N,N]
{
    const int blk = blockIdx.x;
    const int bo  = blk >> 3;
    const int rc  = blk & 7;          // 32-row chunk
    const int b   = bo >> 7;
    const int t   = threadIdx.x;
    const int jb  = (t & 63) << 2;    // base column (fixed per thread)
    const int rr  = t >> 6;           // 0..3

    const float4 vj   = *(const float4*)&uj[bo * NN + jb];  // hoisted off-diagonal values
    const float* uip  = ui + bo * NN;
    const float* adjb = adj + (size_t)b * (NN * NN);
    float*       outp = out + (size_t)bo * (NN * NN);

    const int i0 = (rc << 5) + rr;
    #pragma unroll
    for (int r = 0; r < 8; ++r) {
        const int i = i0 + (r << 2);
        const float s_ii = uip[i];                      // same addr across wave -> broadcast
        const float4 a = *(const float4*)&adjb[i * NN + jb];
        float4 v;
        v.x = (i == jb + 0) ? s_ii : vj.x;
        v.y = (i == jb + 1) ? s_ii : vj.y;
        v.z = (i == jb + 2) ? s_ii : vj.z;
        v.w = (i == jb + 3) ? s_ii : vj.w;
        float4 rs;
        rs.x = a.x * v.x;
        rs.y = a.y * v.y;
        rs.z = a.z * v.z;
        rs.w = a.w * v.w;
        *(float4*)&outp[i * NN + jb] = rs;              // 1 KiB contiguous per wave
    }
}

// ---------------- Fallback (ws too small): round-1 fused kernel --------------------------
__global__ __launch_bounds__(256) void nodeconv_fused(
    const float* __restrict__ adj, const float* __restrict__ node,
    const float* __restrict__ Wi, const float* __restrict__ Wj,
    float* __restrict__ out)
{
    __shared__ float si[NN];
    __shared__ float sj[NN];
    const int bo = blockIdx.x;
    const int b  = bo >> 7;
    const int o  = bo & (NOUT - 1);
    const int t  = threadIdx.x;
    {
        const float* np_ = node + (size_t)(b * NIN) * NN + t;
        const float* wi  = Wi + o * NIN;
        const float* wj  = Wj + o * NIN;
        float ai = 0.f, aj = 0.f;
        #pragma unroll 8
        for (int c = 0; c < NIN; ++c) {
            const float n = np_[(size_t)c * NN];
            ai += wi[c] * n;
            aj += wj[c] * n;
        }
        si[t] = ai;
        sj[t] = aj;
    }
    __syncthreads();
    const int jb   = (t & 63) << 2;
    const int rrow = t >> 6;
    const float4 vj = *(const float4*)&sj[jb];
    const float* adjb = adj + (size_t)b * (NN * NN);
    float*       outp = out + (size_t)bo * (NN * NN);
    #pragma unroll 4
    for (int r = 0; r < 64; ++r) {
        const int i = (r << 2) + rrow;
        const float s_ii = si[i];
        const float4 a = *(const float4*)&adjb[i * NN + jb];
        float4 v;
        v.x = (i == jb + 0) ? s_ii : vj.x;
        v.y = (i == jb + 1) ? s_ii : vj.y;
        v.z = (i == jb + 2) ? s_ii : vj.z;
        v.w = (i == jb + 3) ? s_ii : vj.w;
        float4 rs;
        rs.x = a.x * v.x; rs.y = a.y * v.y; rs.z = a.z * v.z; rs.w = a.w * v.w;
        *(float4*)&outp[i * NN + jb] = rs;
    }
}

extern "C" void kernel_launch(void* const* d_in, const int* in_sizes, int n_in,
                              void* d_out, int out_size, void* d_ws, size_t ws_size,
                              hipStream_t stream) {
    const float* adj  = (const float*)d_in[0];  // [4,1,256,256]
    const float* node = (const float*)d_in[1];  // [4,128,256]
    const float* Wi   = (const float*)d_in[2];  // [128,128]
    const float* Wj   = (const float*)d_in[3];  // [128,128]
    float* out = (float*)d_out;                 // [4,128,256,256]

    const size_t u_elems = (size_t)BB * NOUT * NN;          // 131072
    const size_t need    = 2 * u_elems * sizeof(float);     // 1 MiB

    if (ws_size >= need) {
        float* ui = (float*)d_ws;
        float* uj = ui + u_elems;
        precompute_u<<<dim3(BB * NOUT), dim3(256), 0, stream>>>(node, Wi, Wj, ui, uj);
        stream_out<<<dim3(BB * NOUT * 8), dim3(256), 0, stream>>>(adj, ui, uj, out);
    } else {
        nodeconv_fused<<<dim3(BB * NOUT), dim3(256), 0, stream>>>(adj, node, Wi, Wj, out);
    }
}